// Round 16
// baseline (92.171 us; speedup 1.0000x reference)
//
#include <hip/hip_runtime.h>
#include <hip/hip_bf16.h>
#include <stdint.h>

// Problem constants
#define B_  64
#define C_  3
#define H_  512
#define W_  512
#define OC_ 16
#define OH_ 510
#define OW_ 510

// Tile: 256-thread block -> 64(x) x 16(y); wave wv owns rows 4wv..4wv+3.
// Per wave: 4 groups (2 rows x 32 px), 3 MFMA 32x32x16 each (one per channel).
// M=32 = 16 oc x 2 output rows (v); K=16 = 4 window rows x {kx01-pair, kx2-pair}.
// NO LDS, NO barrier: B-fragments built straight from global (L1/L2-hot).
#define TILES_X_ 8    // ox0 = min(64bx, 446) -> overlap tile at bx=7
#define TILES_Y_ 32   // oy0 = min(16by, 494) -> overlap tile at by=31

typedef __attribute__((ext_vector_type(8)))  short bf16x8;   // MFMA A/B frag
typedef __attribute__((ext_vector_type(16))) float f32x16;   // MFMA C/D frag
typedef __attribute__((ext_vector_type(4)))  float f32x4;

// NaN-safe tanh: 1 - 2/(e^{2x}+1); e=inf -> 1 (no inf/inf NaN).
__device__ __forceinline__ float fast_tanh(float v) {
    float e = __expf(2.0f * v);
    return 1.0f - 2.0f * __builtin_amdgcn_rcpf(e + 1.0f);
}
__device__ __forceinline__ uint16_t bf16u(float f) {
    __hip_bfloat16 h = __float2bfloat16(f);   // RNE
    return __builtin_bit_cast(uint16_t, h);
}
__device__ __forceinline__ uint32_t pack2bf(float v0, float v1) {
    return (uint32_t)bf16u(v0) | ((uint32_t)bf16u(v1) << 16);
}
__device__ __forceinline__ float4 ld_f4(const float* p) {
    float4 v;
    __builtin_memcpy(&v, p, 16);   // dword-aligned global_load_dwordx4
    return v;
}

// ---- prep kernel (R15-verified): A-frags (3 ch) + per-lane bias C-init ----
// ws: [0) A u16[3][64][8] (3072 B); [3072) bias f32[64][16] (4096 B)
// A[m=(oc,v)][k]: pair p=k>>1, h=k&1; wr=p>>1, pk=p&1;
// kx = pk ? (h? INVALID : 2) : h; ky = wr - v; w = wgt[oc][c][ky][kx] or 0.
__global__ void conv_prep(const float* __restrict__ wgt,
                          const float* __restrict__ bias,
                          uint16_t* __restrict__ ws16) {
    const int lane = threadIdx.x;        // 0..63
    const int mr = lane & 31;
    const int oc = mr & 15, v = mr >> 4;
    const int kc = lane >> 5;
    #pragma unroll
    for (int c = 0; c < C_; ++c)
        #pragma unroll
        for (int e = 0; e < 8; ++e) {
            int k  = 8 * kc + e, p = k >> 1, h = k & 1;
            int wr = p >> 1, pk = p & 1;
            int kx = pk ? (h ? -1 : 2) : h;
            int ky = wr - v;
            float w = 0.0f;
            if (kx >= 0 && ky >= 0 && ky <= 2)
                w = wgt[oc * 27 + c * 9 + ky * 3 + kx];
            ws16[(c * 64 + lane) * 8 + e] = bf16u(w);
        }
    // bias C-init: D row = (reg&3) + 8*(reg>>2) + 4*hi -> oc = row&15
    float* bp_ = (float*)(ws16 + 1536);  // byte offset 3072
    const int hi = lane >> 5;
    #pragma unroll
    for (int reg = 0; reg < 16; ++reg) {
        int row = (reg & 3) + 8 * (reg >> 2) + 4 * hi;
        bp_[lane * 16 + reg] = bias[row & 15];
    }
}

__global__ __launch_bounds__(256)
void conv3x3_min_tanh_mfma(const float* __restrict__ x,
                           const uint4* __restrict__ wsv,
                           float* __restrict__ out) {
    const int blk = blockIdx.x;
    const int bx = blk % TILES_X_;
    const int by = (blk / TILES_X_) % TILES_Y_;
    const int b  = blk / (TILES_X_ * TILES_Y_);
    const int ox0 = min(bx * 64, OW_ - 64);   // 446 at bx=7 (overlap tile)
    const int oy0 = min(by * 16, OH_ - 16);   // 494 at by=31 (overlap tile)

    const int tid  = threadIdx.x;
    const int lane = tid & 63;
    const int wv   = tid >> 6;
    const int pcol = lane & 31;          // B: pixel col within 32-px group
    const int hi   = lane >> 5;          // k-chunk AND output-row select v

    const float* xb = x + (size_t)b * (C_ * H_ * W_);

    // ---- baked A-frags + bias C-init (7 coalesced dwordx4, L2/L3-hot) ----
    bf16x8 wfA0 = __builtin_bit_cast(bf16x8, wsv[0 * 64 + lane]);
    bf16x8 wfA1 = __builtin_bit_cast(bf16x8, wsv[1 * 64 + lane]);
    bf16x8 wfA2 = __builtin_bit_cast(bf16x8, wsv[2 * 64 + lane]);
    f32x4 bq0 = __builtin_bit_cast(f32x4, wsv[192 + lane * 4 + 0]);
    f32x4 bq1 = __builtin_bit_cast(f32x4, wsv[192 + lane * 4 + 1]);
    f32x4 bq2 = __builtin_bit_cast(f32x4, wsv[192 + lane * 4 + 2]);
    f32x4 bq3 = __builtin_bit_cast(f32x4, wsv[192 + lane * 4 + 3]);
    f32x16 biasv;
    biasv[0]  = bq0[0]; biasv[1]  = bq0[1]; biasv[2]  = bq0[2]; biasv[3]  = bq0[3];
    biasv[4]  = bq1[0]; biasv[5]  = bq1[1]; biasv[6]  = bq1[2]; biasv[7]  = bq1[3];
    biasv[8]  = bq2[0]; biasv[9]  = bq2[1]; biasv[10] = bq2[2]; biasv[11] = bq2[3];
    biasv[12] = bq3[0]; biasv[13] = bq3[1]; biasv[14] = bq3[2]; biasv[15] = bq3[3];

    const int baddr = (lane ^ 32) << 2;   // hoisted ds_bpermute address
    const size_t obase = ((size_t)b * OH_ + (oy0 + 4 * wv)) * OW_ + ox0;

    // ---- 4 groups: gi = row-pair (0,1), xh = x-half (0,1) ----
    // Lane's window rows: r0 = oy0+4wv+2gi+2hi, r0+1 (<=511 by oy0 clamp).
    // Cols: gx..gx+3; gx = ox0+32xh+pcol <= 509; float4 at cx = gx - s
    // (s = gx>508, only possible at xh=1) then shift-select; 4th value always
    // hits a baked-zero A slot.
#define LDROW(c, r0v, dst0, dst1, xh)                                          \
    {                                                                          \
        const float* p_ = xb + ((size_t)((c) * H_) + (r0v)) * W_ + cx;         \
        float4 l_ = ld_f4(p_);                                                 \
        float a0_ = l_.x, a1_ = l_.y, a2_ = l_.z, a3_ = l_.w;                  \
        if ((xh) == 1) {                                                       \
            a0_ = s ? l_.y : l_.x;                                             \
            a1_ = s ? l_.z : l_.y;                                             \
            a2_ = s ? l_.w : l_.z;                                             \
        }                                                                      \
        dst0 = pack2bf(a0_, a1_);                                              \
        dst1 = pack2bf(a2_, a3_);                                              \
    }

#define GROUP(gi, xh)                                                          \
    {                                                                          \
        const int gx = ox0 + 32 * (xh) + pcol;                                 \
        const int s  = ((xh) == 1) ? (gx > 508) : 0;                           \
        const int cx = gx - s;                                                 \
        const int r0 = oy0 + 4 * wv + 2 * (gi) + 2 * hi;                       \
        uint32_t q0, q1, q2, q3;                                               \
        uint32_t u0, u1, u2, u3;                                               \
        uint32_t w0, w1, w2, w3;                                               \
        LDROW(0, r0,     q0, q1, xh)                                           \
        LDROW(0, r0 + 1, q2, q3, xh)                                           \
        LDROW(1, r0,     u0, u1, xh)                                           \
        LDROW(1, r0 + 1, u2, u3, xh)                                           \
        LDROW(2, r0,     w0, w1, xh)                                           \
        LDROW(2, r0 + 1, w2, w3, xh)                                           \
        bf16x8 tb0 = __builtin_bit_cast(bf16x8, uint4{q0, q1, q2, q3});        \
        bf16x8 tb1 = __builtin_bit_cast(bf16x8, uint4{u0, u1, u2, u3});        \
        bf16x8 tb2 = __builtin_bit_cast(bf16x8, uint4{w0, w1, w2, w3});        \
        f32x16 acc = __builtin_amdgcn_mfma_f32_32x32x16_bf16(wfA0, tb0, biasv, 0, 0, 0); \
        acc = __builtin_amdgcn_mfma_f32_32x32x16_bf16(wfA1, tb1, acc, 0, 0, 0);\
        acc = __builtin_amdgcn_mfma_f32_32x32x16_bf16(wfA2, tb2, acc, 0, 0, 0);\
        float m0 = fminf(fminf(fminf(acc[0], acc[1]), fminf(acc[2], acc[3])),  \
                         fminf(fminf(acc[4], acc[5]), fminf(acc[6], acc[7]))); \
        float m1 = fminf(fminf(fminf(acc[8], acc[9]), fminf(acc[10], acc[11])),\
                         fminf(fminf(acc[12], acc[13]), fminf(acc[14], acc[15])));\
        float snd = hi ? m0 : m1;   /* partner (hi^1) needs my m_{1-hi} */     \
        int bp = __builtin_amdgcn_ds_bpermute(baddr, __builtin_bit_cast(int, snd)); \
        float own = hi ? m1 : m0;                                              \
        float mm = fminf(own, __builtin_bit_cast(float, bp));                  \
        float t_ = fast_tanh(fast_tanh(mm));                                   \
        out[obase + (size_t)((2 * (gi) + hi) * OW_ + 32 * (xh) + pcol)] = t_;  \
    }

    GROUP(0, 0)
    GROUP(0, 1)
    GROUP(1, 0)
    GROUP(1, 1)
#undef GROUP
#undef LDROW
}

extern "C" void kernel_launch(void* const* d_in, const int* in_sizes, int n_in,
                              void* d_out, int out_size, void* d_ws, size_t ws_size,
                              hipStream_t stream) {
    const float* x    = (const float*)d_in[0];
    const float* wgt  = (const float*)d_in[1];
    const float* bias = (const float*)d_in[2];
    float* out = (float*)d_out;

    conv_prep<<<1, 64, 0, stream>>>(wgt, bias, (uint16_t*)d_ws);
    conv3x3_min_tanh_mfma<<<dim3(B_ * TILES_X_ * TILES_Y_), 256, 0, stream>>>(
        x, (const uint4*)d_ws, out);
}

// Round 17
// 78.873 us; speedup vs baseline: 1.1686x; 1.1686x over previous
//
#include <hip/hip_runtime.h>
#include <hip/hip_bf16.h>
#include <stdint.h>

// Problem constants
#define B_  64
#define C_  3
#define H_  512
#define W_  512
#define OC_ 16
#define OH_ 510
#define OW_ 510

// Block = 128 threads = 2 INDEPENDENT waves (no __syncthreads anywhere).
// Each wave: 4 output rows x 64 px; stages its OWN 6 window rows x 3ch into a
// private LDS slice; 4 groups (2 rows x 32 px), 3 MFMA 32x32x16 each.
// M=32 = 16 oc x 2 rows (v); K=16 = 4 window rows x {kx01-pair, kx2-pair}.
#define TILES_X_ 8     // ox0 = min(64bx, 446) overlap tile
#define TILES_Y_ 64    // oy0 = min(8by, 502)  overlap tile (8 rows/block)
#define LINES_   18    // 3 ch x 6 window rows per wave
#define PXW_     68    // u32 pair slots per line (x=0..67; reads reach x=65)

typedef __attribute__((ext_vector_type(8)))  short bf16x8;   // MFMA A/B frag
typedef __attribute__((ext_vector_type(16))) float f32x16;   // MFMA C/D frag
typedef __attribute__((ext_vector_type(4)))  float f32x4;

// NaN-safe tanh: 1 - 2/(e^{2x}+1); e=inf -> 1 (no inf/inf NaN).
__device__ __forceinline__ float fast_tanh(float v) {
    float e = __expf(2.0f * v);
    return 1.0f - 2.0f * __builtin_amdgcn_rcpf(e + 1.0f);
}
__device__ __forceinline__ uint16_t bf16u(float f) {
    __hip_bfloat16 h = __float2bfloat16(f);   // RNE
    return __builtin_bit_cast(uint16_t, h);
}
__device__ __forceinline__ uint32_t pack2bf(float v0, float v1) {
    return (uint32_t)bf16u(v0) | ((uint32_t)bf16u(v1) << 16);
}
__device__ __forceinline__ float4 ld_f4(const float* p) {
    float4 v;
    __builtin_memcpy(&v, p, 16);   // global_load_dwordx4
    return v;
}

// ---- prep kernel (R15-verified): A-frags (3 ch) + per-lane bias C-init ----
// ws: [0) A u16[3][64][8] (3072 B); [3072) bias f32[64][16] (4096 B)
// A[m=(oc,v)][k]: pair p=k>>1, h=k&1; wr=p>>1, pk=p&1;
// kx = pk ? (h? INVALID : 2) : h; ky = wr - v; w = wgt[oc][c][ky][kx] or 0.
__global__ void conv_prep(const float* __restrict__ wgt,
                          const float* __restrict__ bias,
                          uint16_t* __restrict__ ws16) {
    const int lane = threadIdx.x;        // 0..63
    const int mr = lane & 31;
    const int oc = mr & 15, v = mr >> 4;
    const int kc = lane >> 5;
    #pragma unroll
    for (int c = 0; c < C_; ++c)
        #pragma unroll
        for (int e = 0; e < 8; ++e) {
            int k  = 8 * kc + e, p = k >> 1, h = k & 1;
            int wr = p >> 1, pk = p & 1;
            int kx = pk ? (h ? -1 : 2) : h;
            int ky = wr - v;
            float w = 0.0f;
            if (kx >= 0 && ky >= 0 && ky <= 2)
                w = wgt[oc * 27 + c * 9 + ky * 3 + kx];
            ws16[(c * 64 + lane) * 8 + e] = bf16u(w);
        }
    // bias C-init: D row = (reg&3) + 8*(reg>>2) + 4*hi -> oc = row&15
    float* bp_ = (float*)(ws16 + 1536);  // byte offset 3072
    const int hi = lane >> 5;
    #pragma unroll
    for (int reg = 0; reg < 16; ++reg) {
        int row = (reg & 3) + 8 * (reg >> 2) + 4 * hi;
        bp_[lane * 16 + reg] = bias[row & 15];
    }
}

__global__ __launch_bounds__(128)
void conv3x3_min_tanh_mfma(const float* __restrict__ x,
                           const uint4* __restrict__ wsv,
                           float* __restrict__ out) {
    __shared__ uint32_t lds[2 * LINES_ * PXW_];   // 2448 u32 = 9792 B

    const int blk = blockIdx.x;
    const int bx = blk % TILES_X_;
    const int by = (blk / TILES_X_) % TILES_Y_;
    const int b  = blk / (TILES_X_ * TILES_Y_);
    const int ox0 = min(bx * 64, OW_ - 64);   // <= 446
    const int oy0 = min(by * 8,  OH_ - 8);    // <= 502

    const int tid  = threadIdx.x;
    const int lane = tid & 63;
    const int wv   = tid >> 6;           // 0..1 (independent waves)
    const int pcol = lane & 31;
    const int hi   = lane >> 5;

    const int oyw = oy0 + 4 * wv;        // wave's output rows oyw..oyw+3
                                         // window rows oyw..oyw+5 (<=511 exact)
    const float* xb = x + (size_t)b * (C_ * H_ * W_);
    uint32_t* px = lds + wv * (LINES_ * PXW_);   // wave-private slice

    // ---- wave-private staging: 18 lines x 16 float4-chunks (no clamps) ----
    // item i: line = i>>4 (c = line/6, r = line%6), chunk = i&15, x0 = 4*chunk.
    // cols ox0+x0..+4 <= 446+64 = 510 (in-bounds); gy = oyw+r <= 511 exact.
    #pragma unroll
    for (int pass = 0; pass < 5; ++pass) {
        int i = pass * 64 + lane;
        if (pass < 4 || lane < 32) {     // 288 items
            int line = i >> 4;
            int x0   = 4 * (i & 15);
            int c    = (line >= 6) + (line >= 12);
            int r    = line - 6 * c;
            const float* xrow = xb + ((size_t)(c * H_) + (oyw + r)) * W_ + ox0;
            float4 v = ld_f4(xrow + x0);
            float v4 = xrow[x0 + 4];
            uint4 pk;
            pk.x = pack2bf(v.x, v.y);
            pk.y = pack2bf(v.y, v.z);
            pk.z = pack2bf(v.z, v.w);
            pk.w = pack2bf(v.w, v4);
            *reinterpret_cast<uint4*>(&px[line * PXW_ + x0]) = pk;   // 16B-aligned
        }
    }
    // extras: pairs x=64,65 per line (36 items). col <= 511; +1 clamped
    // (clamped value lands only in zero-weight K slots -> finite is enough).
    if (lane < LINES_ * 2) {
        int line = lane >> 1;
        int xx   = 64 + (lane & 1);
        int c    = (line >= 6) + (line >= 12);
        int r    = line - 6 * c;
        const float* xrow = xb + ((size_t)(c * H_) + (oyw + r)) * W_;
        float v0 = xrow[ox0 + xx];                  // <= 511 in-bounds
        float v1 = xrow[min(ox0 + xx + 1, W_ - 1)];
        px[line * PXW_ + xx] = pack2bf(v0, v1);
    }

    // ---- baked A-frags + bias C-init (L1/L2-hot, 7 KB dataset) ----
    bf16x8 wfA0 = __builtin_bit_cast(bf16x8, wsv[0 * 64 + lane]);
    bf16x8 wfA1 = __builtin_bit_cast(bf16x8, wsv[1 * 64 + lane]);
    bf16x8 wfA2 = __builtin_bit_cast(bf16x8, wsv[2 * 64 + lane]);
    f32x16 biasv;
    __builtin_memcpy(&biasv, &wsv[192 + lane * 4], 64);   // 4x dwordx4, no movs

    const int baddr = (lane ^ 32) << 2;   // ds_bpermute address (lane-relative)

    // No __syncthreads: wave-private LDS. Enforce write->read order (rule #18).
    asm volatile("s_waitcnt lgkmcnt(0)" ::: "memory");
    __builtin_amdgcn_sched_barrier(0);

    const size_t obase = ((size_t)b * OH_ + oyw) * OW_ + ox0;

    // ---- 4 groups: gi = row-pair (0,1), xh = x-half (0,1) ----
    // lane's window rows (wave-local): lr = 2gi+2hi, lr+1; pair cols j, j+2.
#define GROUP(gi, xh)                                                          \
    {                                                                          \
        const int j  = pcol + 32 * (xh);                                       \
        const int lr = 2 * (gi) + 2 * hi;                                      \
        const int bc0 = (0 * 6 + lr) * PXW_ + j;                               \
        const int bc1 = (1 * 6 + lr) * PXW_ + j;                               \
        const int bc2 = (2 * 6 + lr) * PXW_ + j;                               \
        uint32_t a0 = px[bc0],         a1 = px[bc0 + 2];                       \
        uint32_t a2 = px[bc0 + PXW_],  a3 = px[bc0 + PXW_ + 2];                \
        uint32_t u0 = px[bc1],         u1 = px[bc1 + 2];                       \
        uint32_t u2 = px[bc1 + PXW_],  u3 = px[bc1 + PXW_ + 2];                \
        uint32_t w0 = px[bc2],         w1 = px[bc2 + 2];                       \
        uint32_t w2 = px[bc2 + PXW_],  w3 = px[bc2 + PXW_ + 2];                \
        bf16x8 tb0 = __builtin_bit_cast(bf16x8, uint4{a0, a1, a2, a3});        \
        bf16x8 tb1 = __builtin_bit_cast(bf16x8, uint4{u0, u1, u2, u3});        \
        bf16x8 tb2 = __builtin_bit_cast(bf16x8, uint4{w0, w1, w2, w3});        \
        f32x16 acc = __builtin_amdgcn_mfma_f32_32x32x16_bf16(wfA0, tb0, biasv, 0, 0, 0); \
        acc = __builtin_amdgcn_mfma_f32_32x32x16_bf16(wfA1, tb1, acc, 0, 0, 0);\
        acc = __builtin_amdgcn_mfma_f32_32x32x16_bf16(wfA2, tb2, acc, 0, 0, 0);\
        float m0 = fminf(fminf(fminf(acc[0], acc[1]), fminf(acc[2], acc[3])),  \
                         fminf(fminf(acc[4], acc[5]), fminf(acc[6], acc[7]))); \
        float m1 = fminf(fminf(fminf(acc[8], acc[9]), fminf(acc[10], acc[11])),\
                         fminf(fminf(acc[12], acc[13]), fminf(acc[14], acc[15])));\
        float snd = hi ? m0 : m1;   /* partner (hi^1) needs my m_{1-hi} */     \
        int bp = __builtin_amdgcn_ds_bpermute(baddr, __builtin_bit_cast(int, snd)); \
        float own = hi ? m1 : m0;                                              \
        float mm = fminf(own, __builtin_bit_cast(float, bp));                  \
        float t_ = fast_tanh(fast_tanh(mm));                                   \
        out[obase + (size_t)((2 * (gi) + hi) * OW_ + 32 * (xh) + pcol)] = t_;  \
    }

    GROUP(0, 0)
    GROUP(0, 1)
    GROUP(1, 0)
    GROUP(1, 1)
#undef GROUP
}

extern "C" void kernel_launch(void* const* d_in, const int* in_sizes, int n_in,
                              void* d_out, int out_size, void* d_ws, size_t ws_size,
                              hipStream_t stream) {
    const float* x    = (const float*)d_in[0];
    const float* wgt  = (const float*)d_in[1];
    const float* bias = (const float*)d_in[2];
    float* out = (float*)d_out;

    conv_prep<<<1, 64, 0, stream>>>(wgt, bias, (uint16_t*)d_ws);
    conv3x3_min_tanh_mfma<<<dim3(B_ * TILES_X_ * TILES_Y_), 128, 0, stream>>>(
        x, (const uint4*)d_ws, out);
}

// Round 18
// 77.521 us; speedup vs baseline: 1.1890x; 1.0174x over previous
//
#include <hip/hip_runtime.h>
#include <hip/hip_bf16.h>
#include <stdint.h>

// Problem constants
#define B_  64
#define C_  3
#define H_  512
#define W_  512
#define OC_ 16
#define OH_ 510
#define OW_ 510

// Block = 128 threads = 2 INDEPENDENT waves (no __syncthreads anywhere).
// Each wave: 64-px x 16-row strip = 4 subtiles of 4 rows, software-pipelined
// through a 3ch x 6-row LDS ring (slot = row mod 6). Per subtile: 4 groups
// (2 rows x 32 px), 3 MFMA 32x32x16 (M=32 = 16 oc x 2 rows; K=16 = 4 window
// rows x {kx01-pair, kx2-pair}) -- R15/R17-verified layout.
#define TILES_X_ 8     // ox0 = min(64bx, 446) overlap tile
#define YBLK_    16    // 2 waves/block -> 32 strips of 16 rows (oyw<=494)
#define PXW_     68    // u32 pair slots per line (x=0..67; reads reach x=65)
#define LPW_     (C_ * 6 * PXW_)   // 18 lines * 68 = wave-private ring

typedef __attribute__((ext_vector_type(8)))  short bf16x8;   // MFMA A/B frag
typedef __attribute__((ext_vector_type(16))) float f32x16;   // MFMA C/D frag
typedef __attribute__((ext_vector_type(4)))  float f32x4;

// NaN-safe tanh: 1 - 2/(e^{2x}+1); e=inf -> 1 (no inf/inf NaN).
__device__ __forceinline__ float fast_tanh(float v) {
    float e = __expf(2.0f * v);
    return 1.0f - 2.0f * __builtin_amdgcn_rcpf(e + 1.0f);
}
__device__ __forceinline__ uint16_t bf16u(float f) {
    __hip_bfloat16 h = __float2bfloat16(f);   // RNE
    return __builtin_bit_cast(uint16_t, h);
}
__device__ __forceinline__ uint32_t pack2bf(float v0, float v1) {
    return (uint32_t)bf16u(v0) | ((uint32_t)bf16u(v1) << 16);
}
__device__ __forceinline__ float4 ld_f4(const float* p) {
    float4 v;
    __builtin_memcpy(&v, p, 16);   // global_load_dwordx4
    return v;
}

// ---- prep kernel (R15-verified): A-frags (3 ch) + per-lane bias C-init ----
// ws: [0) A u16[3][64][8] (3072 B); [3072) bias f32[64][16] (4096 B)
// A[m=(oc,v)][k]: pair p=k>>1, h=k&1; wr=p>>1, pk=p&1;
// kx = pk ? (h? INVALID : 2) : h; ky = wr - v; w = wgt[oc][c][ky][kx] or 0.
__global__ void conv_prep(const float* __restrict__ wgt,
                          const float* __restrict__ bias,
                          uint16_t* __restrict__ ws16) {
    const int lane = threadIdx.x;        // 0..63
    const int mr = lane & 31;
    const int oc = mr & 15, v = mr >> 4;
    const int kc = lane >> 5;
    #pragma unroll
    for (int c = 0; c < C_; ++c)
        #pragma unroll
        for (int e = 0; e < 8; ++e) {
            int k  = 8 * kc + e, p = k >> 1, h = k & 1;
            int wr = p >> 1, pk = p & 1;
            int kx = pk ? (h ? -1 : 2) : h;
            int ky = wr - v;
            float w = 0.0f;
            if (kx >= 0 && ky >= 0 && ky <= 2)
                w = wgt[oc * 27 + c * 9 + ky * 3 + kx];
            ws16[(c * 64 + lane) * 8 + e] = bf16u(w);
        }
    // bias C-init: D row = (reg&3) + 8*(reg>>2) + 4*hi -> oc = row&15
    float* bp_ = (float*)(ws16 + 1536);  // byte offset 3072
    const int hi = lane >> 5;
    #pragma unroll
    for (int reg = 0; reg < 16; ++reg) {
        int row = (reg & 3) + 8 * (reg >> 2) + 4 * hi;
        bp_[lane * 16 + reg] = bias[row & 15];
    }
}

__global__ __launch_bounds__(128)
void conv3x3_min_tanh_mfma(const float* __restrict__ x,
                           const uint4* __restrict__ wsv,
                           float* __restrict__ out) {
    __shared__ uint32_t lds[2 * LPW_];   // 2 x 4896 B

    const int blk = blockIdx.x;
    const int bx = blk % TILES_X_;
    const int by = (blk / TILES_X_) % YBLK_;
    const int b  = blk / (TILES_X_ * YBLK_);
    const int ox0 = min(bx * 64, OW_ - 64);   // <= 446

    const int tid  = threadIdx.x;
    const int lane = tid & 63;
    const int wv   = tid >> 6;           // 0..1 (independent waves)
    const int pcol = lane & 31;
    const int hi   = lane >> 5;

    const int sy  = 2 * by + wv;                 // 0..31
    const int oyw = min(16 * sy, OH_ - 16);      // <= 494; window rows <= 511

    const float* xb = x + (size_t)b * (C_ * H_ * W_);
    uint32_t* px = lds + wv * LPW_;              // wave-private ring

    // ---- prologue: window rows 0..5 -> slots 0..5 (18 lines) ----
    #pragma unroll
    for (int pass = 0; pass < 5; ++pass) {
        int i = pass * 64 + lane;
        if (pass < 4 || lane < 32) {     // 288 items
            int line = i >> 4;           // c*6 + r
            int x0   = 4 * (i & 15);
            int c    = (line >= 6) + (line >= 12);
            int r    = line - 6 * c;
            const float* xrow = xb + ((size_t)(c * H_) + (oyw + r)) * W_ + ox0;
            float4 v = ld_f4(xrow + x0);
            float v4 = xrow[x0 + 4];
            uint4 pk;
            pk.x = pack2bf(v.x, v.y);
            pk.y = pack2bf(v.y, v.z);
            pk.z = pack2bf(v.z, v.w);
            pk.w = pack2bf(v.w, v4);
            *reinterpret_cast<uint4*>(&px[line * PXW_ + x0]) = pk;
        }
    }
    if (lane < 36) {                     // extras x=64,65 per line
        int line = lane >> 1;
        int xx   = 64 + (lane & 1);
        int c    = (line >= 6) + (line >= 12);
        int r    = line - 6 * c;
        const float* xrow = xb + ((size_t)(c * H_) + (oyw + r)) * W_;
        float v0 = xrow[ox0 + xx];
        float v1 = xrow[min(ox0 + xx + 1, W_ - 1)];
        px[line * PXW_ + xx] = pack2bf(v0, v1);
    }

    // ---- baked A-frags + bias C-init (L1/L2-hot, 7 KB dataset) ----
    bf16x8 wfA0 = __builtin_bit_cast(bf16x8, wsv[0 * 64 + lane]);
    bf16x8 wfA1 = __builtin_bit_cast(bf16x8, wsv[1 * 64 + lane]);
    bf16x8 wfA2 = __builtin_bit_cast(bf16x8, wsv[2 * 64 + lane]);
    f32x16 biasv;
    __builtin_memcpy(&biasv, &wsv[192 + lane * 4], 64);

    const int baddr = (lane ^ 32) << 2;
    const size_t obase0 = ((size_t)b * OH_ + oyw) * OW_ + ox0 + pcol;

    asm volatile("s_waitcnt lgkmcnt(0)" ::: "memory");
    __builtin_amdgcn_sched_barrier(0);

    // ---- per subtile t: groups gi (row-pair), xh (x-half); ring slots
    //      s = (4t + 2gi + 2hi (+1)) mod 6 -- compile-time per hi branch ----
#define GROUP(t, gi, xh)                                                       \
    {                                                                          \
        const int j  = pcol + 32 * (xh);                                       \
        const int s0 = hi ? ((4*(t) + 2*(gi) + 2) % 6) : ((4*(t) + 2*(gi)) % 6);     \
        const int s1 = hi ? ((4*(t) + 2*(gi) + 3) % 6) : ((4*(t) + 2*(gi) + 1) % 6); \
        const int b00 = (0 * 6 + s0) * PXW_ + j, b01 = (0 * 6 + s1) * PXW_ + j;\
        const int b10 = (1 * 6 + s0) * PXW_ + j, b11 = (1 * 6 + s1) * PXW_ + j;\
        const int b20 = (2 * 6 + s0) * PXW_ + j, b21 = (2 * 6 + s1) * PXW_ + j;\
        bf16x8 tb0 = __builtin_bit_cast(bf16x8,                                \
            uint4{px[b00], px[b00 + 2], px[b01], px[b01 + 2]});                \
        bf16x8 tb1 = __builtin_bit_cast(bf16x8,                                \
            uint4{px[b10], px[b10 + 2], px[b11], px[b11 + 2]});                \
        bf16x8 tb2 = __builtin_bit_cast(bf16x8,                                \
            uint4{px[b20], px[b20 + 2], px[b21], px[b21 + 2]});                \
        f32x16 acc = __builtin_amdgcn_mfma_f32_32x32x16_bf16(wfA0, tb0, biasv, 0, 0, 0); \
        acc = __builtin_amdgcn_mfma_f32_32x32x16_bf16(wfA1, tb1, acc, 0, 0, 0);\
        acc = __builtin_amdgcn_mfma_f32_32x32x16_bf16(wfA2, tb2, acc, 0, 0, 0);\
        float m0 = fminf(fminf(fminf(acc[0], acc[1]), fminf(acc[2], acc[3])),  \
                         fminf(fminf(acc[4], acc[5]), fminf(acc[6], acc[7]))); \
        float m1 = fminf(fminf(fminf(acc[8], acc[9]), fminf(acc[10], acc[11])),\
                         fminf(fminf(acc[12], acc[13]), fminf(acc[14], acc[15])));\
        float snd = hi ? m0 : m1;                                              \
        int bp = __builtin_amdgcn_ds_bpermute(baddr, __builtin_bit_cast(int, snd)); \
        float own = hi ? m1 : m0;                                              \
        float mm = fminf(own, __builtin_bit_cast(float, bp));                  \
        float t_ = fast_tanh(fast_tanh(mm));                                   \
        out[obase0 + (size_t)(4 * (t) + 2 * (gi) + hi) * OW_ + 32 * (xh)] = t_;\
    }

    // pipelined iteration: issue loads (rows 4t+6..4t+9) -> compute subtile t
    // -> pack+write retired ring slots -> lgkm fence. Pass p == channel p.
#define PIPE_ITER(t)                                                           \
    {                                                                          \
        const int rr_ = lane >> 4, ch_ = lane & 15;                            \
        const int gy_ = oyw + 4 * (t) + 6 + rr_;     /* <= 511 */              \
        const int xo_ = ox0 + 4 * ch_;                                         \
        const float* r0_ = xb + ((size_t)gy_) * W_ + xo_;                      \
        const float* r1_ = xb + ((size_t)(H_ + gy_)) * W_ + xo_;               \
        const float* r2_ = xb + ((size_t)(2 * H_ + gy_)) * W_ + xo_;           \
        float4 L0 = ld_f4(r0_); float E0 = r0_[4];                             \
        float4 L1 = ld_f4(r1_); float E1 = r1_[4];                             \
        float4 L2 = ld_f4(r2_); float E2 = r2_[4];                             \
        float X0 = 0.f, X1 = 0.f;                                              \
        if (lane < 24) {                                                       \
            int le_ = lane >> 1, ce_ = le_ >> 2, re_ = le_ & 3;                \
            int xx_ = 64 + (lane & 1);                                         \
            const float* xr_ = xb + ((size_t)(ce_ * H_) + (oyw + 4*(t) + 6 + re_)) * W_; \
            X0 = xr_[ox0 + xx_];                                               \
            X1 = xr_[min(ox0 + xx_ + 1, W_ - 1)];                              \
        }                                                                      \
        GROUP(t, 0, 0) GROUP(t, 0, 1) GROUP(t, 1, 0) GROUP(t, 1, 1)            \
        {                                                                      \
            const int sb_ = (4 * (t) + 6) % 6;       /* compile-time */        \
            int s_ = sb_ + rr_; s_ = (s_ >= 6) ? s_ - 6 : s_;                  \
            uint4 pk;                                                          \
            pk.x = pack2bf(L0.x, L0.y); pk.y = pack2bf(L0.y, L0.z);            \
            pk.z = pack2bf(L0.z, L0.w); pk.w = pack2bf(L0.w, E0);              \
            *reinterpret_cast<uint4*>(&px[(0 * 6 + s_) * PXW_ + 4 * ch_]) = pk;\
            pk.x = pack2bf(L1.x, L1.y); pk.y = pack2bf(L1.y, L1.z);            \
            pk.z = pack2bf(L1.z, L1.w); pk.w = pack2bf(L1.w, E1);              \
            *reinterpret_cast<uint4*>(&px[(1 * 6 + s_) * PXW_ + 4 * ch_]) = pk;\
            pk.x = pack2bf(L2.x, L2.y); pk.y = pack2bf(L2.y, L2.z);            \
            pk.z = pack2bf(L2.z, L2.w); pk.w = pack2bf(L2.w, E2);              \
            *reinterpret_cast<uint4*>(&px[(2 * 6 + s_) * PXW_ + 4 * ch_]) = pk;\
            if (lane < 24) {                                                   \
                int le_ = lane >> 1, ce_ = le_ >> 2, re_ = le_ & 3;            \
                int xx_ = 64 + (lane & 1);                                     \
                int se_ = sb_ + re_; se_ = (se_ >= 6) ? se_ - 6 : se_;         \
                px[(ce_ * 6 + se_) * PXW_ + xx_] = pack2bf(X0, X1);            \
            }                                                                  \
        }                                                                      \
        asm volatile("s_waitcnt lgkmcnt(0)" ::: "memory");                     \
        __builtin_amdgcn_sched_barrier(0);                                     \
    }

    PIPE_ITER(0)
    PIPE_ITER(1)
    PIPE_ITER(2)
    GROUP(3, 0, 0) GROUP(3, 0, 1) GROUP(3, 1, 0) GROUP(3, 1, 1)
#undef PIPE_ITER
#undef GROUP
}

extern "C" void kernel_launch(void* const* d_in, const int* in_sizes, int n_in,
                              void* d_out, int out_size, void* d_ws, size_t ws_size,
                              hipStream_t stream) {
    const float* x    = (const float*)d_in[0];
    const float* wgt  = (const float*)d_in[1];
    const float* bias = (const float*)d_in[2];
    float* out = (float*)d_out;

    conv_prep<<<1, 64, 0, stream>>>(wgt, bias, (uint16_t*)d_ws);
    conv3x3_min_tanh_mfma<<<dim3(B_ * TILES_X_ * YBLK_), 128, 0, stream>>>(
        x, (const uint4*)d_ws, out);
}

// Round 19
// 76.808 us; speedup vs baseline: 1.2000x; 1.0093x over previous
//
#include <hip/hip_runtime.h>
#include <hip/hip_bf16.h>
#include <stdint.h>

// Problem constants
#define B_  64
#define C_  3
#define H_  512
#define W_  512
#define OC_ 16
#define OH_ 510
#define OW_ 510

// Block = 128 threads = 2 INDEPENDENT waves (no __syncthreads anywhere).
// Each wave: 64-px x 16-row strip = 4 subtiles of 4 rows, software-pipelined
// through a 3ch x 6-row LDS ring (slot = row mod 6). Per subtile: 4 groups
// (2 rows x 32 px), 3 MFMA 32x32x16. M=32 rows carry (v,oc) PERMUTED so that
// C-layout row=(reg&3)+8*(reg>>2)+4*hi gives: hi half-wave == v, regs == all
// 16 oc -> channel-min is PURE IN-LANE (no bpermute).
//   row r: v = (r>>2)&1, oc = (r&3) | ((r>>3)<<2)
#define TILES_X_ 8     // ox0 = min(64bx, 446) overlap tile
#define YBLK_    16    // 2 waves/block -> 32 strips of 16 rows (oyw<=494)
#define PXW_     68    // u32 pair slots per line (x=0..67; reads reach x=65)
#define LPW_     (C_ * 6 * PXW_)   // 18 lines * 68 = wave-private ring

typedef __attribute__((ext_vector_type(8)))  short bf16x8;   // MFMA A/B frag
typedef __attribute__((ext_vector_type(16))) float f32x16;   // MFMA C/D frag
typedef __attribute__((ext_vector_type(4)))  float f32x4;

// NaN-safe tanh: 1 - 2/(e^{2x}+1); e=inf -> 1 (no inf/inf NaN).
__device__ __forceinline__ float fast_tanh(float v) {
    float e = __expf(2.0f * v);
    return 1.0f - 2.0f * __builtin_amdgcn_rcpf(e + 1.0f);
}
__device__ __forceinline__ uint16_t bf16u(float f) {
    __hip_bfloat16 h = __float2bfloat16(f);   // RNE
    return __builtin_bit_cast(uint16_t, h);
}
__device__ __forceinline__ uint32_t pack2bf(float v0, float v1) {
    return (uint32_t)bf16u(v0) | ((uint32_t)bf16u(v1) << 16);
}
__device__ __forceinline__ float4 ld_f4(const float* p) {
    float4 v;
    __builtin_memcpy(&v, p, 16);   // global_load_dwordx4
    return v;
}

// ---- prep kernel: A-frags (3 ch, PERMUTED rows) + per-lane bias C-init ----
// ws: [0) A u16[3][64][8] (3072 B); [3072) bias f32[64][16] (4096 B)
// A[m][k]: m -> v=(m>>2)&1, oc=(m&3)|((m>>3)<<2). k: pair p=k>>1, h=k&1;
// wr=p>>1, pk=p&1; kx = pk ? (h? INVALID : 2) : h; ky = wr - v;
// w = wgt[oc][c][ky][kx] or 0.
__global__ void conv_prep(const float* __restrict__ wgt,
                          const float* __restrict__ bias,
                          uint16_t* __restrict__ ws16) {
    const int lane = threadIdx.x;        // 0..63
    const int mr = lane & 31;
    const int v  = (mr >> 2) & 1;
    const int oc = (mr & 3) | ((mr >> 3) << 2);
    const int kc = lane >> 5;
    #pragma unroll
    for (int c = 0; c < C_; ++c)
        #pragma unroll
        for (int e = 0; e < 8; ++e) {
            int k  = 8 * kc + e, p = k >> 1, h = k & 1;
            int wr = p >> 1, pk = p & 1;
            int kx = pk ? (h ? -1 : 2) : h;
            int ky = wr - v;
            float w = 0.0f;
            if (kx >= 0 && ky >= 0 && ky <= 2)
                w = wgt[oc * 27 + c * 9 + ky * 3 + kx];
            ws16[(c * 64 + lane) * 8 + e] = bf16u(w);
        }
    // bias C-init: D row = (reg&3)+8*(reg>>2)+4*hi -> oc = (row&3)|((row>>3)<<2)
    float* bp_ = (float*)(ws16 + 1536);  // byte offset 3072
    const int hi = lane >> 5;
    #pragma unroll
    for (int reg = 0; reg < 16; ++reg) {
        int row = (reg & 3) + 8 * (reg >> 2) + 4 * hi;
        bp_[lane * 16 + reg] = bias[(row & 3) | ((row >> 3) << 2)];
    }
}

__global__ __launch_bounds__(128)
void conv3x3_min_tanh_mfma(const float* __restrict__ x,
                           const uint4* __restrict__ wsv,
                           float* __restrict__ out) {
    __shared__ uint32_t lds[2 * LPW_];   // 2 x 4896 B

    const int blk = blockIdx.x;
    const int bx = blk % TILES_X_;
    const int by = (blk / TILES_X_) % YBLK_;
    const int b  = blk / (TILES_X_ * YBLK_);
    const int ox0 = min(bx * 64, OW_ - 64);   // <= 446

    const int tid  = threadIdx.x;
    const int lane = tid & 63;
    const int wv   = tid >> 6;           // 0..1 (independent waves)
    const int pcol = lane & 31;
    const int hi   = lane >> 5;

    const int sy  = 2 * by + wv;                 // 0..31
    const int oyw = min(16 * sy, OH_ - 16);      // <= 494; window rows <= 511

    const float* xb = x + (size_t)b * (C_ * H_ * W_);
    uint32_t* px = lds + wv * LPW_;              // wave-private ring

    // ---- prologue: window rows 0..5 -> slots 0..5 (18 lines) ----
    #pragma unroll
    for (int pass = 0; pass < 5; ++pass) {
        int i = pass * 64 + lane;
        if (pass < 4 || lane < 32) {     // 288 items
            int line = i >> 4;           // c*6 + r
            int x0   = 4 * (i & 15);
            int c    = (line >= 6) + (line >= 12);
            int r    = line - 6 * c;
            const float* xrow = xb + ((size_t)(c * H_) + (oyw + r)) * W_ + ox0;
            float4 v = ld_f4(xrow + x0);
            float v4 = xrow[x0 + 4];
            uint4 pk;
            pk.x = pack2bf(v.x, v.y);
            pk.y = pack2bf(v.y, v.z);
            pk.z = pack2bf(v.z, v.w);
            pk.w = pack2bf(v.w, v4);
            *reinterpret_cast<uint4*>(&px[line * PXW_ + x0]) = pk;
        }
    }
    if (lane < 36) {                     // extras x=64,65 per line
        int line = lane >> 1;
        int xx   = 64 + (lane & 1);
        int c    = (line >= 6) + (line >= 12);
        int r    = line - 6 * c;
        const float* xrow = xb + ((size_t)(c * H_) + (oyw + r)) * W_;
        float v0 = xrow[ox0 + xx];
        float v1 = xrow[min(ox0 + xx + 1, W_ - 1)];
        px[line * PXW_ + xx] = pack2bf(v0, v1);
    }

    // ---- baked A-frags + bias C-init (L1/L2-hot, 7 KB dataset) ----
    bf16x8 wfA0 = __builtin_bit_cast(bf16x8, wsv[0 * 64 + lane]);
    bf16x8 wfA1 = __builtin_bit_cast(bf16x8, wsv[1 * 64 + lane]);
    bf16x8 wfA2 = __builtin_bit_cast(bf16x8, wsv[2 * 64 + lane]);
    f32x16 biasv;
    __builtin_memcpy(&biasv, &wsv[192 + lane * 4], 64);

    const size_t obase0 = ((size_t)b * OH_ + oyw) * OW_ + ox0 + pcol;

    asm volatile("s_waitcnt lgkmcnt(0)" ::: "memory");
    __builtin_amdgcn_sched_barrier(0);

    // ---- per subtile t: groups gi (row-pair), xh (x-half); ring slots
    //      s = (4t + 2gi + 2hi (+1)) mod 6 -- compile-time per hi branch.
    //      Epilogue: PURE IN-LANE 15-fmin (A-row permutation), no bpermute. ----
#define GROUP(t, gi, xh)                                                       \
    {                                                                          \
        const int j  = pcol + 32 * (xh);                                       \
        const int s0 = hi ? ((4*(t) + 2*(gi) + 2) % 6) : ((4*(t) + 2*(gi)) % 6);     \
        const int s1 = hi ? ((4*(t) + 2*(gi) + 3) % 6) : ((4*(t) + 2*(gi) + 1) % 6); \
        const int b00 = (0 * 6 + s0) * PXW_ + j, b01 = (0 * 6 + s1) * PXW_ + j;\
        const int b10 = (1 * 6 + s0) * PXW_ + j, b11 = (1 * 6 + s1) * PXW_ + j;\
        const int b20 = (2 * 6 + s0) * PXW_ + j, b21 = (2 * 6 + s1) * PXW_ + j;\
        bf16x8 tb0 = __builtin_bit_cast(bf16x8,                                \
            uint4{px[b00], px[b00 + 2], px[b01], px[b01 + 2]});                \
        bf16x8 tb1 = __builtin_bit_cast(bf16x8,                                \
            uint4{px[b10], px[b10 + 2], px[b11], px[b11 + 2]});                \
        bf16x8 tb2 = __builtin_bit_cast(bf16x8,                                \
            uint4{px[b20], px[b20 + 2], px[b21], px[b21 + 2]});                \
        f32x16 acc = __builtin_amdgcn_mfma_f32_32x32x16_bf16(wfA0, tb0, biasv, 0, 0, 0); \
        acc = __builtin_amdgcn_mfma_f32_32x32x16_bf16(wfA1, tb1, acc, 0, 0, 0);\
        acc = __builtin_amdgcn_mfma_f32_32x32x16_bf16(wfA2, tb2, acc, 0, 0, 0);\
        float n0 = fminf(acc[0], acc[1]),   n1 = fminf(acc[2], acc[3]);        \
        float n2 = fminf(acc[4], acc[5]),   n3 = fminf(acc[6], acc[7]);        \
        float n4 = fminf(acc[8], acc[9]),   n5 = fminf(acc[10], acc[11]);      \
        float n6 = fminf(acc[12], acc[13]), n7 = fminf(acc[14], acc[15]);      \
        float mm = fminf(fminf(fminf(n0, n1), fminf(n2, n3)),                  \
                         fminf(fminf(n4, n5), fminf(n6, n7)));                 \
        float t_ = fast_tanh(fast_tanh(mm));                                   \
        out[obase0 + (size_t)(4 * (t) + 2 * (gi) + hi) * OW_ + 32 * (xh)] = t_;\
    }

    // pipelined iteration: issue loads (rows 4t+6..4t+9) -> compute subtile t
    // -> pack+write retired ring slots -> lgkm fence.
#define PIPE_ITER(t)                                                           \
    {                                                                          \
        const int rr_ = lane >> 4, ch_ = lane & 15;                            \
        const int gy_ = oyw + 4 * (t) + 6 + rr_;     /* <= 511 */              \
        const int xo_ = ox0 + 4 * ch_;                                         \
        const float* r0_ = xb + ((size_t)gy_) * W_ + xo_;                      \
        const float* r1_ = xb + ((size_t)(H_ + gy_)) * W_ + xo_;               \
        const float* r2_ = xb + ((size_t)(2 * H_ + gy_)) * W_ + xo_;           \
        float4 L0 = ld_f4(r0_); float E0 = r0_[4];                             \
        float4 L1 = ld_f4(r1_); float E1 = r1_[4];                             \
        float4 L2 = ld_f4(r2_); float E2 = r2_[4];                             \
        float X0 = 0.f, X1 = 0.f;                                              \
        if (lane < 24) {                                                       \
            int le_ = lane >> 1, ce_ = le_ >> 2, re_ = le_ & 3;                \
            int xx_ = 64 + (lane & 1);                                         \
            const float* xr_ = xb + ((size_t)(ce_ * H_) + (oyw + 4*(t) + 6 + re_)) * W_; \
            X0 = xr_[ox0 + xx_];                                               \
            X1 = xr_[min(ox0 + xx_ + 1, W_ - 1)];                              \
        }                                                                      \
        GROUP(t, 0, 0) GROUP(t, 0, 1) GROUP(t, 1, 0) GROUP(t, 1, 1)            \
        {                                                                      \
            const int sb_ = (4 * (t) + 6) % 6;       /* compile-time */        \
            int s_ = sb_ + rr_; s_ = (s_ >= 6) ? s_ - 6 : s_;                  \
            uint4 pk;                                                          \
            pk.x = pack2bf(L0.x, L0.y); pk.y = pack2bf(L0.y, L0.z);            \
            pk.z = pack2bf(L0.z, L0.w); pk.w = pack2bf(L0.w, E0);              \
            *reinterpret_cast<uint4*>(&px[(0 * 6 + s_) * PXW_ + 4 * ch_]) = pk;\
            pk.x = pack2bf(L1.x, L1.y); pk.y = pack2bf(L1.y, L1.z);            \
            pk.z = pack2bf(L1.z, L1.w); pk.w = pack2bf(L1.w, E1);              \
            *reinterpret_cast<uint4*>(&px[(1 * 6 + s_) * PXW_ + 4 * ch_]) = pk;\
            pk.x = pack2bf(L2.x, L2.y); pk.y = pack2bf(L2.y, L2.z);            \
            pk.z = pack2bf(L2.z, L2.w); pk.w = pack2bf(L2.w, E2);              \
            *reinterpret_cast<uint4*>(&px[(2 * 6 + s_) * PXW_ + 4 * ch_]) = pk;\
            if (lane < 24) {                                                   \
                int le_ = lane >> 1, ce_ = le_ >> 2, re_ = le_ & 3;            \
                int xx_ = 64 + (lane & 1);                                     \
                int se_ = sb_ + re_; se_ = (se_ >= 6) ? se_ - 6 : se_;         \
                px[(ce_ * 6 + se_) * PXW_ + xx_] = pack2bf(X0, X1);            \
            }                                                                  \
        }                                                                      \
        asm volatile("s_waitcnt lgkmcnt(0)" ::: "memory");                     \
        __builtin_amdgcn_sched_barrier(0);                                     \
    }

    PIPE_ITER(0)
    PIPE_ITER(1)
    PIPE_ITER(2)
    GROUP(3, 0, 0) GROUP(3, 0, 1) GROUP(3, 1, 0) GROUP(3, 1, 1)
#undef PIPE_ITER
#undef GROUP
}

extern "C" void kernel_launch(void* const* d_in, const int* in_sizes, int n_in,
                              void* d_out, int out_size, void* d_ws, size_t ws_size,
                              hipStream_t stream) {
    const float* x    = (const float*)d_in[0];
    const float* wgt  = (const float*)d_in[1];
    const float* bias = (const float*)d_in[2];
    float* out = (float*)d_out;

    conv_prep<<<1, 64, 0, stream>>>(wgt, bias, (uint16_t*)d_ws);
    conv3x3_min_tanh_mfma<<<dim3(B_ * TILES_X_ * YBLK_), 128, 0, stream>>>(
        x, (const uint4*)d_ws, out);
}